// Round 7
// baseline (56.687 us; speedup 1.0000x reference)
//
#include <hip/hip_runtime.h>
#include <math.h>

// 64 graphs x 512 nodes, K+1=17 (incl self), 128 RBF channels, radius=8.
#define NPG   512
#define KK    17
#define RBFN  128
#define TPB   128
#define WPB   2
#define TPC   2                        // targets per chunk (per wave)
#define NSC   32                       // scanners per target
#define CPS   16                       // candidates per scanner
#define NCH   4                        // chunks per wave -> 8 targets/wave
#define TGT_PER_WAVE (TPC * NCH)       // 8
#define TGT_PER_BLK  (WPB * TGT_PER_WAVE)  // 16
#define BPG   (NPG / TGT_PER_BLK)      // 32 -> 2048 blocks
#define LSTR  20                       // lane-list stride (dwords), 16B-aligned

// R6 post-mortem: 55.6us vs ~42us write-drain floor. Residue: prologue
// (scan0+merge0, no stores ~6us) + bursty store phases (2 of 5). R7: fold
// repr-row stores INTO the merge extraction steps -- at step k all lanes
// know the winner, so each 32-lane half computes+stores that row's float4
// immediately (1KB/wave-step, 68 steps spread over ~70% of the timeline).
// Scan shrinks to 16 candidates/scanner (16-deep CE chain): prologue ~1.5us.
// Keep proven: u32 truncated keys (src err <= 511 < 655 thresh; exact d2
// recomputed at emit), fire-and-forget stores, single block barrier.
#define WAVE_SYNC()                                      \
  do {                                                   \
    asm volatile("s_waitcnt lgkmcnt(0)" ::: "memory");   \
    __builtin_amdgcn_sched_barrier(0);                   \
  } while (0)

__device__ __forceinline__ unsigned gmin32(unsigned v) {
  // xor-butterfly min over each 32-lane half (BitMode swizzle: xor 1..16)
  unsigned t;
  t = (unsigned)__builtin_amdgcn_ds_swizzle((int)v, 0x041F); v = v < t ? v : t;
  t = (unsigned)__builtin_amdgcn_ds_swizzle((int)v, 0x081F); v = v < t ? v : t;
  t = (unsigned)__builtin_amdgcn_ds_swizzle((int)v, 0x101F); v = v < t ? v : t;
  t = (unsigned)__builtin_amdgcn_ds_swizzle((int)v, 0x201F); v = v < t ? v : t;
  t = (unsigned)__builtin_amdgcn_ds_swizzle((int)v, 0x401F); v = v < t ? v : t;
  return v;
}

__global__ __launch_bounds__(TPB, 4) void fused_kernel(
    const float* __restrict__ pos, const float* __restrict__ bias,
    float* __restrict__ out, int E) {
  __shared__ float4 ps[NPG];                            // 8 KB
  __shared__ __align__(16) unsigned LA[WPB][64][LSTR];  // 10 KB lane lists

  const int g = blockIdx.x / BPG;
  const int p = blockIdx.x % BPG;
  const float* gp = pos + (size_t)g * NPG * 3;
  for (int i = threadIdx.x; i < NPG; i += TPB)
    ps[i] = make_float4(gp[3 * i], gp[3 * i + 1], gp[3 * i + 2], 0.0f);
  __syncthreads();                                      // only block barrier

  const int w = threadIdx.x >> 6;
  const int lane = threadIdx.x & 63;
  const int tl = lane >> 5;                             // target-in-chunk 0..1
  const int q = lane & 31;                              // scanner / channel grp

  float* __restrict__ srcp = out;
  float* __restrict__ dstp = out + (size_t)E;
  float* __restrict__ repr = out + 2 * (size_t)E;
  float* __restrict__ mskp = out + 130 * (size_t)E;
  float4* __restrict__ repr4 = reinterpret_cast<float4*>(repr);

  const float step = 8.0f / 127.0f;
  const float coeff = -0.5f / (step * step);
  const int c0 = q << 2;                                // 4 channels per lane
  const float4 bv = *reinterpret_cast<const float4*>(bias + c0);
  const float o0 = (float)(c0 + 0) * step, o1 = (float)(c0 + 1) * step,
              o2 = (float)(c0 + 2) * step, o3 = (float)(c0 + 3) * step;

  const int tbase = p * TGT_PER_BLK + w * TGT_PER_WAVE;
  const int goff = g * NPG;

  unsigned b0, b1, b2, b3, b4, b5, b6, b7, b8, b9, b10, b11, b12, b13, b14,
      b15;
  float px, py, pz;

#define CE(B)                                    \
  {                                              \
    const unsigned mn_ = key < (B) ? key : (B);  \
    const unsigned mx_ = key < (B) ? (B) : key;  \
    (B) = mn_;                                   \
    key = mx_;                                   \
  }

  for (int c = 0; c < NCH; ++c) {
    // ---- scan: 16 candidates/scanner, sorted-16 in named regs ----
    const int t = tbase + c * TPC + tl;
    {
      const float4 me = ps[t];
      px = me.x; py = me.y; pz = me.z;
    }
    b0 = b1 = b2 = b3 = b4 = b5 = b6 = b7 = b8 = b9 = b10 = b11 = b12 = b13 =
        b14 = b15 = 0xFFFFFFFFu;
#pragma unroll 4
    for (int jj = 0; jj < CPS; ++jj) {
      const int j = (jj << 5) | q;
      const float4 c4 = ps[j];
      const float dx = __fsub_rn(px, c4.x);
      const float dy = __fsub_rn(py, c4.y);
      const float dz = __fsub_rn(pz, c4.z);
      const float d2 = __fadd_rn(
          __fadd_rn(__fmul_rn(dx, dx), __fmul_rn(dy, dy)), __fmul_rn(dz, dz));
      unsigned key = (__float_as_uint(d2) & 0xFFFFFE00u) | (unsigned)j;
      CE(b0) CE(b1) CE(b2) CE(b3) CE(b4) CE(b5) CE(b6) CE(b7) CE(b8)
      CE(b9) CE(b10) CE(b11) CE(b12) CE(b13) CE(b14) CE(b15)
    }

    // ---- dump lane-private sorted list + sentinel ----
    {
      uint4* Lv = reinterpret_cast<uint4*>(&LA[w][lane][0]);
      Lv[0] = make_uint4(b0, b1, b2, b3);
      Lv[1] = make_uint4(b4, b5, b6, b7);
      Lv[2] = make_uint4(b8, b9, b10, b11);
      Lv[3] = make_uint4(b12, b13, b14, b15);
      LA[w][lane][16] = 0xFFFFFFFFu;   // sentinel (lane can win <= 16 times)
    }
    WAVE_SYNC();

    // ---- merge (17 extraction steps) with FUSED row stores ----
    const int node = goff + t;
    const size_t ebase = (size_t)node * KK;
    float4* __restrict__ rb = repr4 + (size_t)node * (KK * RBFN / 4);
    const unsigned* L = &LA[w][lane][0];
    int i = 0;
    unsigned h = L[0];
    unsigned cap = 0;
#pragma unroll
    for (int k = 0; k < KK; ++k) {
      const unsigned mn = gmin32(h);          // uniform across the 32-half
      cap = (q == k) ? mn : cap;              // round-robin capture
      // exact d2 for the winner (keys truncated); broadcast LDS read
      const int jv = (int)(mn & 511u);
      const float4 cj = ps[jv];
      const float dx = __fsub_rn(px, cj.x);
      const float dy = __fsub_rn(py, cj.y);
      const float dz = __fsub_rn(pz, cj.z);
      const float d2 = __fadd_rn(
          __fadd_rn(__fmul_rn(dx, dx), __fmul_rn(dy, dy)), __fmul_rn(dz, dz));
      const float dv = __fsqrt_rn(fmaxf(d2, 1e-12f));
      const float okf = (dv <= 8.0f) ? 1.0f : 0.0f;
      float4 o;
      { const float d_ = __fsub_rn(dv, o0); o.x = (__expf(coeff * d_ * d_) + bv.x) * okf; }
      { const float d_ = __fsub_rn(dv, o1); o.y = (__expf(coeff * d_ * d_) + bv.y) * okf; }
      { const float d_ = __fsub_rn(dv, o2); o.z = (__expf(coeff * d_ * d_) + bv.z) * okf; }
      { const float d_ = __fsub_rn(dv, o3); o.w = (__expf(coeff * d_ * d_) + bv.w) * okf; }
      rb[k * 32 + q] = o;                     // fire-and-forget, coalesced
      // advance: keys unique -> exactly one lane steps its list
      const bool adv = (h == mn);
      i += adv;
      const unsigned nxt = L[i];
      h = adv ? nxt : h;
    }
    // ---- emit src/dst/mask (coalesced, lanes q<17 of each half) ----
    if (q < KK) {
      const int jv = (int)(cap & 511u);
      const float4 cj = ps[jv];
      const float dx = __fsub_rn(px, cj.x);
      const float dy = __fsub_rn(py, cj.y);
      const float dz = __fsub_rn(pz, cj.z);
      const float d2 = __fadd_rn(
          __fadd_rn(__fmul_rn(dx, dx), __fmul_rn(dy, dy)), __fmul_rn(dz, dz));
      const float dv = __fsqrt_rn(fmaxf(d2, 1e-12f));
      srcp[ebase + q] = (float)(jv + goff);
      dstp[ebase + q] = (float)node;
      mskp[ebase + q] = (dv <= 8.0f) ? 1.0f : 0.0f;
    }
    WAVE_SYNC();  // merge's L reads drained before next chunk's dump
  }
#undef CE
}

extern "C" void kernel_launch(void* const* d_in, const int* in_sizes, int n_in,
                              void* d_out, int out_size, void* d_ws, size_t ws_size,
                              hipStream_t stream) {
  const float* pos = (const float*)d_in[0];
  const float* bias = (const float*)d_in[1];
  (void)n_in; (void)d_ws; (void)ws_size; (void)out_size;

  const int N = in_sizes[0] / 3;  // 32768
  const int B = N / NPG;          // 64
  const int E = N * KK;           // 557056
  float* out = (float*)d_out;

  fused_kernel<<<B * BPG, TPB, 0, stream>>>(pos, bias, out, E);
}

// Round 8
// 52.008 us; speedup vs baseline: 1.0900x; 1.0900x over previous
//
#include <hip/hip_runtime.h>
#include <math.h>

// 64 graphs x 512 nodes, K+1=17 (incl self), 128 RBF channels, radius=8.
#define NPG   512
#define KK    17
#define RBFN  128
#define TPB   128
#define WPB   2
#define TPC   2                        // targets per chunk (per wave)
#define NSC   32                       // scanners per target
#define CPS   16                       // candidates per scanner
#define NCH   2                        // chunks per wave -> 4 targets/wave
#define TGT_PER_WAVE (TPC * NCH)       // 4
#define TGT_PER_BLK  (WPB * TGT_PER_WAVE)  // 8
#define BPG   (NPG / TGT_PER_BLK)      // 64 -> 4096 blocks

// R7 post-mortem: neutral vs R6 (55.6/56.7us vs ~42-46us write floor).
// Residue = merge's serial swizzle chain unhidden at 4 waves/SIMD; LDS
// lists (10KB) are what capped occupancy. R8: NO LDS lists -- sorted-16
// kept in named regs through the merge; the winning lane shifts its queue
// down with 16 predicated v_cndmask (compile-time indices -> no scratch).
// LDS = ps only (8.5KB) -> 16 blocks/CU x 2 waves = 32 waves/CU = 8/SIMD
// (2x R7), launch_bounds(128,8) caps VGPR at 64. Merge latency + store
// bursts hide under 8-way wave interleave. Keep proven: u32 truncated keys
// (src err <= 511 < 655 thresh; exact d2 recomputed at emit), fused row
// stores in merge steps, fire-and-forget stores, single block barrier.

__device__ __forceinline__ unsigned gmin32(unsigned v) {
  // xor-butterfly min over each 32-lane half (BitMode swizzle: xor 1..16)
  unsigned t;
  t = (unsigned)__builtin_amdgcn_ds_swizzle((int)v, 0x041F); v = v < t ? v : t;
  t = (unsigned)__builtin_amdgcn_ds_swizzle((int)v, 0x081F); v = v < t ? v : t;
  t = (unsigned)__builtin_amdgcn_ds_swizzle((int)v, 0x101F); v = v < t ? v : t;
  t = (unsigned)__builtin_amdgcn_ds_swizzle((int)v, 0x201F); v = v < t ? v : t;
  t = (unsigned)__builtin_amdgcn_ds_swizzle((int)v, 0x401F); v = v < t ? v : t;
  return v;
}

__global__ __launch_bounds__(TPB, 8) void fused_kernel(
    const float* __restrict__ pos, const float* __restrict__ bias,
    float* __restrict__ out, int E) {
  __shared__ float4 ps[NPG];  // 8 KB -- the ONLY LDS

  const int g = blockIdx.x / BPG;
  const int p = blockIdx.x % BPG;
  const float* gp = pos + (size_t)g * NPG * 3;
  for (int i = threadIdx.x; i < NPG; i += TPB)
    ps[i] = make_float4(gp[3 * i], gp[3 * i + 1], gp[3 * i + 2], 0.0f);
  __syncthreads();  // only block barrier

  const int w = threadIdx.x >> 6;
  const int lane = threadIdx.x & 63;
  const int tl = lane >> 5;   // target-in-chunk 0..1
  const int q = lane & 31;    // scanner / channel group

  float* __restrict__ srcp = out;
  float* __restrict__ dstp = out + (size_t)E;
  float* __restrict__ repr = out + 2 * (size_t)E;
  float* __restrict__ mskp = out + 130 * (size_t)E;
  float4* __restrict__ repr4 = reinterpret_cast<float4*>(repr);

  const float step = 8.0f / 127.0f;
  const float coeff = -0.5f / (step * step);
  const int c0 = q << 2;  // 4 channels per lane
  const float4 bv = *reinterpret_cast<const float4*>(bias + c0);
  const float o0 = (float)(c0 + 0) * step, o1 = (float)(c0 + 1) * step,
              o2 = (float)(c0 + 2) * step, o3 = (float)(c0 + 3) * step;

  const int tbase = p * TGT_PER_BLK + w * TGT_PER_WAVE;
  const int goff = g * NPG;
  const unsigned SENT = 0xFFFFFFFFu;

  unsigned b0, b1, b2, b3, b4, b5, b6, b7, b8, b9, b10, b11, b12, b13, b14,
      b15;
  float px, py, pz;

#define CE(B)                                    \
  {                                              \
    const unsigned mn_ = key < (B) ? key : (B);  \
    const unsigned mx_ = key < (B) ? (B) : key;  \
    (B) = mn_;                                   \
    key = mx_;                                   \
  }

  for (int c = 0; c < NCH; ++c) {
    // ---- scan: 16 candidates/scanner, sorted-16 in named regs ----
    const int t = tbase + c * TPC + tl;
    {
      const float4 me = ps[t];
      px = me.x; py = me.y; pz = me.z;
    }
    b0 = b1 = b2 = b3 = b4 = b5 = b6 = b7 = b8 = b9 = b10 = b11 = b12 = b13 =
        b14 = b15 = SENT;
#pragma unroll 4
    for (int jj = 0; jj < CPS; ++jj) {
      const int j = (jj << 5) | q;
      const float4 c4 = ps[j];
      const float dx = __fsub_rn(px, c4.x);
      const float dy = __fsub_rn(py, c4.y);
      const float dz = __fsub_rn(pz, c4.z);
      const float d2 = __fadd_rn(
          __fadd_rn(__fmul_rn(dx, dx), __fmul_rn(dy, dy)), __fmul_rn(dz, dz));
      unsigned key = (__float_as_uint(d2) & 0xFFFFFE00u) | (unsigned)j;
      CE(b0) CE(b1) CE(b2) CE(b3) CE(b4) CE(b5) CE(b6) CE(b7) CE(b8)
      CE(b9) CE(b10) CE(b11) CE(b12) CE(b13) CE(b14) CE(b15)
    }

    // ---- merge: 17 extraction steps, register shift-down queue,
    //      fused RBF row store at each step ----
    const int node = goff + t;
    const size_t ebase = (size_t)node * KK;
    float4* __restrict__ rb = repr4 + (size_t)node * (KK * RBFN / 4);
    unsigned cap = 0;
#pragma unroll
    for (int k = 0; k < KK; ++k) {
      const unsigned mn = gmin32(b0);  // uniform across the 32-half
      cap = (q == k) ? mn : cap;       // round-robin capture for src/dst/mask
      // exact d2 for the winner (keys truncated); broadcast LDS read
      const int jv = (int)(mn & 511u);
      const float4 cj = ps[jv];
      const float dx = __fsub_rn(px, cj.x);
      const float dy = __fsub_rn(py, cj.y);
      const float dz = __fsub_rn(pz, cj.z);
      const float d2 = __fadd_rn(
          __fadd_rn(__fmul_rn(dx, dx), __fmul_rn(dy, dy)), __fmul_rn(dz, dz));
      const float dv = __fsqrt_rn(fmaxf(d2, 1e-12f));
      const float okf = (dv <= 8.0f) ? 1.0f : 0.0f;
      float4 o;
      { const float d_ = __fsub_rn(dv, o0); o.x = (__expf(coeff * d_ * d_) + bv.x) * okf; }
      { const float d_ = __fsub_rn(dv, o1); o.y = (__expf(coeff * d_ * d_) + bv.y) * okf; }
      { const float d_ = __fsub_rn(dv, o2); o.z = (__expf(coeff * d_ * d_) + bv.z) * okf; }
      { const float d_ = __fsub_rn(dv, o3); o.w = (__expf(coeff * d_ * d_) + bv.w) * okf; }
      rb[k * 32 + q] = o;  // fire-and-forget, coalesced 512B per half
      // advance: winning lane shifts its queue down (ascending order reads
      // the OLD next value -- all compile-time indices, pure VALU)
      const bool adv = (b0 == mn);
      b0  = adv ? b1  : b0;   b1  = adv ? b2  : b1;
      b2  = adv ? b3  : b2;   b3  = adv ? b4  : b3;
      b4  = adv ? b5  : b4;   b5  = adv ? b6  : b5;
      b6  = adv ? b7  : b6;   b7  = adv ? b8  : b7;
      b8  = adv ? b9  : b8;   b9  = adv ? b10 : b9;
      b10 = adv ? b11 : b10;  b11 = adv ? b12 : b11;
      b12 = adv ? b13 : b12;  b13 = adv ? b14 : b13;
      b14 = adv ? b15 : b14;  b15 = adv ? SENT : b15;
    }
    // ---- emit src/dst/mask (coalesced, lanes q<17 of each half) ----
    if (q < KK) {
      const int jv = (int)(cap & 511u);
      const float4 cj = ps[jv];
      const float dx = __fsub_rn(px, cj.x);
      const float dy = __fsub_rn(py, cj.y);
      const float dz = __fsub_rn(pz, cj.z);
      const float d2 = __fadd_rn(
          __fadd_rn(__fmul_rn(dx, dx), __fmul_rn(dy, dy)), __fmul_rn(dz, dz));
      const float dv = __fsqrt_rn(fmaxf(d2, 1e-12f));
      srcp[ebase + q] = (float)(jv + goff);
      dstp[ebase + q] = (float)node;
      mskp[ebase + q] = (dv <= 8.0f) ? 1.0f : 0.0f;
    }
  }
#undef CE
}

extern "C" void kernel_launch(void* const* d_in, const int* in_sizes, int n_in,
                              void* d_out, int out_size, void* d_ws, size_t ws_size,
                              hipStream_t stream) {
  const float* pos = (const float*)d_in[0];
  const float* bias = (const float*)d_in[1];
  (void)n_in; (void)d_ws; (void)ws_size; (void)out_size;

  const int N = in_sizes[0] / 3;  // 32768
  const int B = N / NPG;          // 64
  const int E = N * KK;           // 557056
  float* out = (float*)d_out;

  fused_kernel<<<B * BPG, TPB, 0, stream>>>(pos, bias, out, E);
}